// Round 24
// baseline (326.129 us; speedup 1.0000x reference)
//
#include <hip/hip_runtime.h>
#include <hip/hip_bf16.h>
#include <math.h>

#define HEAD_DIM 128
#define NH 16
#define NKV 4
#define BB 4
#define TT 2048
#define DD 2048
#define ROWS (BB*TT)   // 8192

typedef unsigned short u16;
typedef unsigned int u32;
typedef __attribute__((ext_vector_type(8))) short short8;
typedef __attribute__((ext_vector_type(4))) float f32x4;
typedef __attribute__((ext_vector_type(16))) float f32x16;
typedef __attribute__((ext_vector_type(4))) unsigned short u16x4;

__device__ __forceinline__ float bf2f(u16 u) {
    union { unsigned int i; float f; } v; v.i = ((unsigned int)u) << 16; return v.f;
}
__device__ __forceinline__ u16 f2bf(float f) {
    union { float f; unsigned int i; } v; v.f = f;
    unsigned int r = v.i + 0x7FFFu + ((v.i >> 16) & 1u);   // round-to-nearest-even
    return (u16)(r >> 16);
}
__device__ __forceinline__ f32x4 mfma16(short8 a, short8 b, f32x4 c) {
    return __builtin_amdgcn_mfma_f32_16x16x32_bf16(a, b, c, 0, 0, 0);
}
__device__ __forceinline__ f32x16 mfma32(short8 a, short8 b, f32x16 c) {
    return __builtin_amdgcn_mfma_f32_32x32x16_bf16(a, b, c, 0, 0, 0);
}
__device__ __forceinline__ f32x16 zero16() {
    f32x16 z;
    #pragma unroll
    for (int i = 0; i < 16; ++i) z[i] = 0.f;
    return z;
}
// async global->LDS, 16B per lane; lds dest wave-uniform (HW adds lane*16)
__device__ __forceinline__ void gload_lds16(const u16* g, u16* l) {
    __builtin_amdgcn_global_load_lds(
        (const __attribute__((address_space(1))) unsigned int*)(const void*)g,
        (__attribute__((address_space(3))) unsigned int*)(void*)l, 16, 0, 0);
}

// ---------------------------------------------------------------------------
// fp32 -> bf16 cast (single-range)
// ---------------------------------------------------------------------------
__global__ __launch_bounds__(256)
void cast_f2b(const float* __restrict__ in, u16* __restrict__ out, int n)
{
    int i = (blockIdx.x * 256 + threadIdx.x) * 4;
    if (i >= n) return;
    float4 v = *(const float4*)(in + i);
    u16x4 o;
    o.x = f2bf(v.x); o.y = f2bf(v.y); o.z = f2bf(v.z); o.w = f2bf(v.w);
    *(u16x4*)(out + i) = o;
}

// ---------------------------------------------------------------------------
// prep_all: fused {x, q_w, k_w, v_w} casts + rope table build
// ---------------------------------------------------------------------------
__global__ __launch_bounds__(256)
void prep_all(const float* __restrict__ x,  const float* __restrict__ qw,
              const float* __restrict__ kw, const float* __restrict__ vw,
              u16* __restrict__ xh, u16* __restrict__ wq, u16* __restrict__ wkv,
              float* __restrict__ cs, float* __restrict__ sn, float base)
{
    const int bid = blockIdx.x, tid = threadIdx.x;
    if (bid < 22528) {
        const float* src; u16* dst; int i4;
        if (bid < 16384)      { src = x;  dst = xh;            i4 = bid; }
        else if (bid < 20480) { src = qw; dst = wq;            i4 = bid - 16384; }
        else if (bid < 21504) { src = kw; dst = wkv;           i4 = bid - 20480; }
        else                  { src = vw; dst = wkv + 1048576; i4 = bid - 21504; }
        int i = (i4 * 256 + tid) * 4;
        float4 v = *(const float4*)(src + i);
        u16x4 o;
        o.x = f2bf(v.x); o.y = f2bf(v.y); o.z = f2bf(v.z); o.w = f2bf(v.w);
        *(u16x4*)(dst + i) = o;
    } else {
        int idx = (bid - 22528) * 256 + tid;     // < TT*64
        int t = idx >> 6;
        int d = idx & 63;
        float inv = powf(base, -(float)(2 * d) / 128.0f);
        float f = (float)t * inv;
        cs[idx] = cosf(f);
        sn[idx] = sinf(f);
    }
}

// ---------------------------------------------------------------------------
// V transpose+relayout: vbh [B,T,KVH,128] -> vt [B,KVH, T/64, 128, 64] (bf16)
// kt-tiled; per-32 key permutation (bits 2<->3), proven rounds 5-23.
// ---------------------------------------------------------------------------
__global__ __launch_bounds__(256)
void transpose_v(const u16* __restrict__ vbh, u16* __restrict__ vtb)
{
    __shared__ u16 tile[64][72];
    const int tb = blockIdx.x;
    const int db = blockIdx.y;
    const int z  = blockIdx.z;        // b*NKV + kvh
    const int tid = threadIdx.x;

    {
        const int r = tid >> 2, cq = tid & 3;
        const u16* src = vbh + ((size_t)(((z >> 2) * TT + tb * 64 + r) * NKV + (z & 3))) * 128
                             + db * 64 + cq * 16;
        short8 s0 = *(const short8*)(src);
        short8 s1 = *(const short8*)(src + 8);
        #pragma unroll
        for (int e = 0; e < 8; ++e) tile[r][cq * 16 + e]     = (u16)s0[e];
        #pragma unroll
        for (int e = 0; e < 8; ++e) tile[r][cq * 16 + 8 + e] = (u16)s1[e];
    }
    __syncthreads();
    {
        const int d = tid >> 2, tq = tid & 3;
        __attribute__((aligned(16))) u16 tmp[16];
        #pragma unroll
        for (int e = 0; e < 16; ++e) {
            int esw = (e & 3) | ((e & 4) << 1) | ((e & 8) >> 1);  // swap bits 2,3
            tmp[e] = tile[tq * 16 + esw][d];
        }
        u16* dst = vtb + (((size_t)(z * (TT / 64) + tb) * 128 + (db * 64 + d)) << 6) + tq * 16;
        *(short8*)(dst)     = ((short8*)tmp)[0];
        *(short8*)(dst + 8) = ((short8*)tmp)[1];
    }
}

// ---------------------------------------------------------------------------
// 256-tile GEMM, TWO K-TILES PER SYNC WINDOW (round-24): NT=32 tiles but only
// 16 barrier windows. Per window: compute buf0,buf1 (both resident) ->
// barrier -> restage both -> vmcnt(0) -> barrier. Tests the per-window
// fixed-cost theory (KV N=1024 == Q N=2048 at ~130us => work is ~2% of tile
// time). Pair-row conflict-free LDS (round-16 proven) unchanged.
// OUTMODE: 2 = fp32 C0 (N=2048)
//          3 = Q fused epilogue: RMSNorm+RoPE+gain -> C0 = q2 [B,NH,T,128]
//          4 = KV: K cols (bni<4) fused RMSNorm+RoPE -> C0 = kk [B,KVH,T,128];
//              V cols (bni>=4) plain bf16 -> C1 = vbh [B,T,KVH,128]
// ---------------------------------------------------------------------------
template<int BN, int OUTMODE>
__global__ __launch_bounds__(512, 2)
void gemm256(const u16* __restrict__ A, const u16* __restrict__ W,
             void* __restrict__ C0, void* __restrict__ C1,
             const float* __restrict__ CS, const float* __restrict__ SN,
             const float* __restrict__ GAIN, float PRE)
{
    constexpr int WN    = (BN == 256) ? 4 : 2;
    constexpr int MR    = (BN == 256) ? 8 : 4;
    constexpr int WROW  = (BN == 256) ? 128 : 64;
    constexpr int NT    = DD / 64;               // 32 K-tiles
    constexpr int NBI   = (BN == 256) ? 4 : 2;   // B stage issues per wave
    constexpr int BPR   = BN / 16;               // B pair-rows per wave

    __shared__ u16 LDSall[2 * 128 * 128 + 2 * (BN / 2) * 128];
    __shared__ float Sred[1024];
    u16* AsL = LDSall;
    u16* BsL = LDSall + 2 * 128 * 128;

    const int tid = threadIdx.x;
    const int w = tid >> 6, l = tid & 63;
    const int lq = l & 15, lg = l >> 4;
    const int wmi = (WN == 4) ? (w >> 2) : (w >> 1);
    const int wni = w & (WN - 1);

    int bmi, bni;
    {
        const int bid = blockIdx.x;
        const int wg = (bid & 7) * 32 + (bid >> 3);
        const int st = wg >> 2, wi = wg & 3;
        const int sty = st >> 2, stx = st & 3;
        bmi = sty * 2 + (wi >> 1);
        bni = stx * 2 + (wi & 1);
    }
    const int bm = bmi * 256, bn = bni * BN;

    const int sro = l >> 4;          // staging row-in-issue 0..3
    const int sch = l & 15;          // staging 16B chunk 0..15

    f32x4 acc[MR][4];
    #pragma unroll
    for (int m = 0; m < MR; ++m)
        #pragma unroll
        for (int n = 0; n < 4; ++n) acc[m][n] = (f32x4){0.f, 0.f, 0.f, 0.f};

    auto stage = [&](int buf, int t) {
        const size_t ko = (size_t)t * 64;
        u16* Ad = AsL + buf * (128 * 128);
        u16* Bd = BsL + buf * ((BN / 2) * 128);
        #pragma unroll
        for (int j = 0; j < 4; ++j) {
            int rp = w * 16 + j * 4 + sro;
            int cg = sch ^ (rp & 15);
            gload_lds16(A + (size_t)(bm + 2 * rp + (cg >> 3)) * DD + ko + (cg & 7) * 8,
                        Ad + (w * 16 + j * 4) * 128);
        }
        #pragma unroll
        for (int j = 0; j < NBI; ++j) {
            int rp = w * BPR + j * 4 + sro;
            int cg = sch ^ (rp & 15);
            gload_lds16(W + (size_t)(bn + 2 * rp + (cg >> 3)) * DD + ko + (cg & 7) * 8,
                        Bd + (w * BPR + j * 4) * 128);
        }
    };

    stage(0, 0);
    stage(1, 1);
    asm volatile("s_waitcnt vmcnt(0)" ::: "memory");
    __builtin_amdgcn_s_barrier();
    __builtin_amdgcn_sched_barrier(0);

    const int mh = lq >> 1;              // pair-row sub-offset
    const int e8 = (lq & 1) << 3;        // parity -> chunk bit 3
    for (int t = 0; t < NT; t += 2) {
        // ---- compute both resident buffers (2 K-tiles, no barrier between) ----
        #pragma unroll
        for (int half = 0; half < 2; ++half) {
            const u16* Ab = AsL + half * (128 * 128);
            const u16* Bb = BsL + half * ((BN / 2) * 128);
            #pragma unroll
            for (int ks = 0; ks < 2; ++ks) {
                short8 af[MR], bf[4];
                #pragma unroll
                for (int m = 0; m < MR; ++m) {
                    int rp = wmi * (WROW / 2) + m * 8 + mh;
                    af[m] = *(const short8*)(Ab + rp * 128 + (((e8 + ks * 4 + lg) ^ (rp & 15)) << 3));
                }
                #pragma unroll
                for (int n = 0; n < 4; ++n) {
                    int rp = wni * 32 + n * 8 + mh;
                    bf[n] = *(const short8*)(Bb + rp * 128 + (((e8 + ks * 4 + lg) ^ (rp & 15)) << 3));
                }
                __builtin_amdgcn_s_setprio(1);
                #pragma unroll
                for (int m = 0; m < MR; ++m)
                    #pragma unroll
                    for (int n = 0; n < 4; ++n)
                        acc[m][n] = mfma16(af[m], bf[n], acc[m][n]);
                __builtin_amdgcn_s_setprio(0);
            }
        }

        // ---- window advance: restage both buffers ----
        if (t + 2 < NT) {
            __builtin_amdgcn_sched_barrier(0);
            __builtin_amdgcn_s_barrier();          // all waves done reading both
            stage(0, t + 2);
            stage(1, t + 3);
            asm volatile("s_waitcnt vmcnt(0)" ::: "memory");
            __builtin_amdgcn_s_barrier();          // both tiles visible
            __builtin_amdgcn_sched_barrier(0);
        }
    }

    if constexpr (OUTMODE == 2) {
        #pragma unroll
        for (int m = 0; m < MR; ++m) {
            int grow = bm + wmi * WROW + m * 16 + lg * 4;
            #pragma unroll
            for (int n = 0; n < 4; ++n) {
                int col = wni * 64 + n * 16 + lq;
                #pragma unroll
                for (int q = 0; q < 4; ++q)
                    ((float*)C0)[(size_t)(grow + q) * 2048 + bn + col] = acc[m][n][q];
            }
        }
    } else {
        const bool isK = (OUTMODE == 3) ? true : (bni < 4);
        u16* E = LDSall;
        constexpr int RS = (OUTMODE == 3) ? 256 : 128;   // E row stride (u16)
        constexpr int CM = (OUTMODE == 3) ? 31 : 15;     // chunk XOR mask

        if (isK) {
            __syncthreads();            // all waves done with K-loop LDS reads
            // (A) per-row sumsq partials
            #pragma unroll
            for (int m = 0; m < MR; ++m) {
                f32x4 ps = acc[m][0] * acc[m][0];
                #pragma unroll
                for (int n = 1; n < 4; ++n) ps += acc[m][n] * acc[m][n];
                #pragma unroll
                for (int q = 0; q < 4; ++q) {
                    float v = ps[q];
                    v += __shfl_xor(v, 1, 64);
                    v += __shfl_xor(v, 2, 64);
                    v += __shfl_xor(v, 4, 64);
                    v += __shfl_xor(v, 8, 64);
                    if (lq == 0) {
                        int lr = m * 16 + lg * 4 + q;
                        if constexpr (OUTMODE == 3)
                            Sred[wmi * 512 + lr * 4 + (wni >> 1) * 2 + (wni & 1)] = v;
                        else
                            Sred[wmi * 128 + lr * 2 + (wni & 1)] = v;
                    }
                }
            }
            __syncthreads();
            // (B) normalize -> E row-major bf16 (chunk-XOR swizzled)
            #pragma unroll
            for (int m = 0; m < MR; ++m) {
                f32x4 rs4;
                #pragma unroll
                for (int q = 0; q < 4; ++q) {
                    int lr = m * 16 + lg * 4 + q;
                    float tot;
                    if constexpr (OUTMODE == 3)
                        tot = Sred[wmi * 512 + lr * 4 + (wni >> 1) * 2]
                            + Sred[wmi * 512 + lr * 4 + (wni >> 1) * 2 + 1];
                    else
                        tot = Sred[wmi * 128 + lr * 2]
                            + Sred[wmi * 128 + lr * 2 + 1];
                    rs4[q] = 1.0f / sqrtf(tot * (1.0f / 128.0f) + 1.1920929e-7f);
                }
                #pragma unroll
                for (int n = 0; n < 4; ++n) {
                    #pragma unroll
                    for (int q = 0; q < 4; ++q) {
                        int rloc = wmi * WROW + m * 16 + lg * 4 + q;
                        int col  = wni * 64 + n * 16 + lq;
                        int eoff = rloc * RS + ((((col >> 3) ^ (rloc & CM)) << 3) | (col & 7));
                        E[eoff] = f2bf(acc[m][n][q] * rs4[q]);
                    }
                }
            }
            __syncthreads();
            // (C) rotate-half rope + coalesced vector store
            constexpr int NU = (OUTMODE == 3) ? 8 : 4;
            #pragma unroll
            for (int u = 0; u < NU; ++u) {
                int gu = u * 512 + tid;
                int pair = gu & 7;
                int rloc = (gu >> 3) & 255;
                int hsub = (OUTMODE == 3) ? (gu >> 11) : 0;
                int d0 = pair * 8;
                int cl = hsub * 128 + d0;
                int ch = cl + 64;
                short8 lo = *(const short8*)&E[rloc * RS + (((cl >> 3) ^ (rloc & CM)) << 3)];
                short8 hi2 = *(const short8*)&E[rloc * RS + (((ch >> 3) ^ (rloc & CM)) << 3)];
                int grow = bm + rloc;
                int t = grow & 2047, bb = grow >> 11;
                float4 c0 = *(const float4*)&CS[t * 64 + d0];
                float4 c1 = *(const float4*)&CS[t * 64 + d0 + 4];
                float4 s0 = *(const float4*)&SN[t * 64 + d0];
                float4 s1 = *(const float4*)&SN[t * 64 + d0 + 4];
                float cc[8] = {c0.x, c0.y, c0.z, c0.w, c1.x, c1.y, c1.z, c1.w};
                float ssv[8] = {s0.x, s0.y, s0.z, s0.w, s1.x, s1.y, s1.z, s1.w};
                float g = 1.f;
                size_t obase;
                if constexpr (OUTMODE == 3) {
                    int h = (bn >> 7) + hsub;
                    g = GAIN[h] * PRE;
                    obase = ((size_t)(bb * NH + h) * TT + t) << 7;
                } else {
                    obase = ((size_t)(bb * NKV + bni) * TT + t) << 7;
                }
                union { u16 e[8]; short8 s8; } o1, o2;
                #pragma unroll
                for (int e = 0; e < 8; ++e) {
                    float x1 = bf2f((u16)lo[e]);
                    float x2 = bf2f((u16)hi2[e]);
                    o1.e[e] = f2bf((x1 * cc[e] + x2 * ssv[e]) * g);
                    o2.e[e] = f2bf((-x1 * ssv[e] + x2 * cc[e]) * g);
                }
                *(short8*)((u16*)C0 + obase + d0)      = o1.s8;
                *(short8*)((u16*)C0 + obase + 64 + d0) = o2.s8;
            }
        } else {
            // V columns (OUTMODE 4, bni>=4): plain bf16 -> vbh [B,T,KVH,128]
            #pragma unroll
            for (int m = 0; m < MR; ++m) {
                int growb = bm + wmi * WROW + m * 16 + lg * 4;
                #pragma unroll
                for (int n = 0; n < 4; ++n) {
                    int cg = bn + wni * 64 + n * 16 + lq - 512;
                    #pragma unroll
                    for (int q = 0; q < 4; ++q)
                        ((u16*)C1)[(size_t)(growb + q) * 512 + cg] = f2bf(acc[m][n][q]);
                }
            }
        }
    }
}

// ---------------------------------------------------------------------------
// Causal attention — round-16/18 version (counted-vmcnt staging, conflict-free
// 16-chunk XOR LDS, fold-balanced, XCD-mapped). Proven passed. Unchanged.
// ---------------------------------------------------------------------------
__global__ __launch_bounds__(256, 2)
void attn_mfma(const u16* __restrict__ qg,   // [B,NH,T,128] head-major, pre-scaled
               const u16* __restrict__ kg,   // [B,KVH,T,128]
               const u16* __restrict__ vtg,  // [B,KVH,T/64,128,64] key-permuted
               u16* __restrict__ yg)         // [B,T,NH,128]
{
    __shared__ u16 Ks[2][64 * 128];   // [key][256B]      16-chunk XOR
    __shared__ u16 Vs[2][64 * 128];   // [d-pair][256B]   16-chunk XOR

    const int tid = threadIdx.x, wid = tid >> 6, l = tid & 63;
    const int lq = l & 31, hi = l >> 5, hi4 = hi << 2;

    const int bid = blockIdx.x;
    const int xcd  = bid & 7;
    const int s    = bid >> 3;
    const int gsub = s >> 5;
    const int hh   = (s >> 3) & 3;
    const int fold = s & 7;
    const int g    = xcd + (gsub << 3);
    const int b = g >> 2, kvh = g & 3;
    const int h = kvh * 4 + hh;

    const u16* kg_bh = kg + (((size_t)g * TT) << 7);
    const u16* vt_bh = vtg + (size_t)g * (TT / 64) * 8192;
    const u16* q_bh  = qg + (((size_t)(b * NH + h) * TT) << 7);

    const int nta = 2 * fold + 2;
    const int NT  = 34;

    const int sro = l >> 4;              // row-in-issue 0..3
    const int sch = l & 15;              // 16B chunk 0..15

    auto stage = [&](int buf, int kt) {
        #pragma unroll
        for (int i = 0; i < 4; ++i) {
            int kr = wid * 16 + i * 4 + sro;
            int cgk = sch ^ (kr & 15);
            gload_lds16(kg_bh + (((size_t)(kt * 64 + kr)) << 7) + (cgk << 3),
                        &Ks[buf][(wid * 16 + i * 4) << 7]);
            int rp = wid * 16 + i * 4 + sro;
            int cgv = sch ^ (rp & 15);
            gload_lds16(vt_bh + (size_t)kt * 8192 + ((2 * rp + (cgv >> 3)) << 6) + ((cgv & 7) << 3),
                        &Vs[buf][(wid * 16 + i * 4) << 7]);
        }
    };

    stage(0, 0);
    stage(1, 1);
    asm volatile("s_waitcnt vmcnt(8)" ::: "memory");
    __builtin_amdgcn_s_barrier();
    __builtin_amdgcn_sched_barrier(0);

    int step = 0;

    for (int seg = 0; seg < 2; ++seg) {
        const int qblk = seg ? (15 - fold) : fold;
        const int nseg = seg ? (32 - 2 * fold) : nta;
        const int qrow = qblk * 128 + wid * 32 + lq;
        const int diag = (qblk * 128 + wid * 32) >> 6;

        const u16* qptr = q_bh + ((size_t)qrow << 7) + hi * 8;
        short8 qf[8];
        #pragma unroll
        for (int q = 0; q < 8; ++q)
            qf[q] = *(const short8*)(qptr + q * 16);

        f32x16 accO[4];
        #pragma unroll
        for (int d = 0; d < 4; ++d) accO[d] = zero16();
        float m2 = -1e30f, lr = 0.f;

        for (int kt = 0; kt < nseg; ++kt, ++step) {
            const int buf = step & 1;

            if (kt <= diag) {
                // ---- S^T = K·Q (16 MFMA) ----
                const u16* Kc = Ks[buf];
                f32x16 accS0 = zero16(), accS1 = zero16();
                __builtin_amdgcn_s_setprio(1);
                #pragma unroll
                for (int ss = 0; ss < 8; ++ss) {
                    int c = ((2 * ss + hi) ^ (lq & 15)) << 3;
                    short8 kf0 = *(const short8*)(Kc + (lq << 7) + c);
                    accS0 = mfma32(kf0, qf[ss], accS0);
                    short8 kf1 = *(const short8*)(Kc + ((32 + lq) << 7) + c);
                    accS1 = mfma32(kf1, qf[ss], accS1);
                }
                __builtin_amdgcn_s_setprio(0);

                // ---- scores + causal mask (diag tile only) ----
                float p[32];
                if (kt == diag) {
                    #pragma unroll
                    for (int r = 0; r < 16; ++r) {
                        int key0 = kt * 64 + (r & 3) + 8 * (r >> 2) + hi4;
                        p[r]      = (key0      > qrow) ? -INFINITY : accS0[r];
                        p[16 + r] = (key0 + 32 > qrow) ? -INFINITY : accS1[r];
                    }
                } else {
                    #pragma unroll
                    for (int r = 0; r < 16; ++r) { p[r] = accS0[r]; p[16 + r] = accS1[r]; }
                }

                // ---- row max ----
                float t16[16];
                #pragma unroll
                for (int i = 0; i < 16; ++i) t16[i] = fmaxf(p[i], p[i + 16]);
                #pragma unroll
                for (int i = 0; i < 8; ++i) t16[i] = fmaxf(t16[i], t16[i + 8]);
                #pragma unroll
                for (int i = 0; i < 4; ++i) t16[i] = fmaxf(t16[i], t16[i + 4]);
                float pm = fmaxf(fmaxf(t16[0], t16[1]), fmaxf(t16[2], t16[3]));
                pm = fmaxf(pm, __shfl_xor(pm, 32, 64));

                // ---- defer-max ----
                float mn = m2;
                if (!__all(pm - m2 <= 8.0f)) {
                    mn = fmaxf(m2, pm);
                    float al = exp2f(m2 - mn);
                    lr *= al;
                    #pragma unroll
                    for (int d = 0; d < 4; ++d) accO[d] *= al;
                    m2 = mn;
                }

                // ---- exp2 + row sum ----
                #pragma unroll
                for (int r = 0; r < 32; ++r) p[r] = exp2f(p[r] - mn);
                #pragma unroll
                for (int i = 0; i < 16; ++i) t16[i] = p[i] + p[i + 16];
                #pragma unroll
                for (int i = 0; i < 8; ++i) t16[i] += t16[i + 8];
                #pragma unroll
                for (int i = 0; i < 4; ++i) t16[i] += t16[i + 4];
                float rs = (t16[0] + t16[1]) + (t16[2] + t16[3]);
                rs += __shfl_xor(rs, 32, 64);
                lr += rs;

                // ---- P -> bf16 B-fragments via packed cvt (RTNE) ----
                short8 pfrag[4];
                #pragma unroll
                for (int kb = 0; kb < 2; ++kb)
                    #pragma unroll
                    for (int c = 0; c < 2; ++c) {
                        union { u32 u[4]; short8 s8; } f;
                        #pragma unroll
                        for (int j = 0; j < 4; ++j) {
                            __hip_bfloat162 hb = __float22bfloat162_rn(
                                make_float2(p[kb * 16 + 8 * c + 2 * j],
                                            p[kb * 16 + 8 * c + 2 * j + 1]));
                            f.u[j] = *reinterpret_cast<u32*>(&hb);
                        }
                        pfrag[kb * 2 + c] = f.s8;
                    }

                // ---- O^T += V^T · P^T (16 MFMA), pair-row V reads ----
                const u16* Vc = Vs[buf];
                const int rv = lq >> 1;
                const int ev = (lq & 1) << 3;
                #pragma unroll
                for (int d = 0; d < 4; ++d) {
                    const u16* vr8 = Vc + ((d * 16 + rv) << 7);
                    short8 vf0 = *(const short8*)(vr8 + (((ev + 0 + hi) ^ rv) << 3));
                    short8 vf1 = *(const short8*)(vr8 + (((ev + 2 + hi) ^ rv) << 3));
                    short8 vf2 = *(const short8*)(vr8 + (((ev + 4 + hi) ^ rv) << 3));
                    short8 vf3 = *(const short8*)(vr8 + (((ev + 6 + hi) ^ rv) << 3));
                    __builtin_amdgcn_s_setprio(1);
                    accO[d] = mfma32(vf0, pfrag[0], accO[d]);
                    accO[d] = mfma32(vf1, pfrag[1], accO[d]);
                    accO[d] = mfma32(vf2, pfrag[2], accO[d]);
                    accO[d] = mfma32(vf3, pfrag[3], accO[d]);
                    __builtin_amdgcn_s_setprio(0);
                }
            }

            // ---- pipeline advance (all waves, uniform) ----
            if (step + 1 < NT) {
                __builtin_amdgcn_sched_barrier(0);
                __builtin_amdgcn_s_barrier();
                if (step + 2 < NT) {
                    int tn = step + 2;
                    stage(buf, (tn < nta) ? tn : tn - nta);
                    asm volatile("s_waitcnt vmcnt(8)" ::: "memory");
                } else {
                    asm volatile("s_waitcnt vmcnt(0)" ::: "memory");
                }
                __builtin_amdgcn_s_barrier();
                __builtin_amdgcn_sched_barrier(0);
            }
        }

        // ---- segment epilogue: normalize (lr lane-uniform) and store ----
        float inv = 1.0f / lr;
        u16* yrow = yg + ((size_t)((b * TT + qrow) * NH + h) << 7);
        #pragma unroll
        for (int d = 0; d < 4; ++d)
            #pragma unroll
            for (int r = 0; r < 4; ++r) {
                u16x4 o;
                #pragma unroll
                for (int q = 0; q < 4; ++q) o[q] = f2bf(accO[d][4 * r + q] * inv);
                *(u16x4*)(yrow + d * 32 + 8 * r + hi4) = o;
            }
    }
}

// ---------------------------------------------------------------------------
extern "C" void kernel_launch(void* const* d_in, const int* in_sizes, int n_in,
                              void* d_out, int out_size, void* d_ws, size_t ws_size,
                              hipStream_t stream)
{
    const float* x      = (const float*)d_in[0];
    const float* q_w    = (const float*)d_in[1];
    const float* k_w    = (const float*)d_in[2];
    const float* v_w    = (const float*)d_in[3];
    const float* out_w  = (const float*)d_in[4];
    const float* q_gain = (const float*)d_in[5];
    float* out = (float*)d_out;

    char* ws = (char*)d_ws;
    u16* q2   = (u16*)(ws);                       // [0,32M)   fused Q out [B,NH,T,128]
    u16* xh   = (u16*)(ws + 33554432ull);         // [32,64M)  x bf16; later y
    u16* wqkv = (u16*)(ws + 67108864ull);         // [64,76.6M) wq+wkv; wq later kk
    u16* vtb  = (u16*)(ws + 79691776ull);         // [76.6..84.6M) V^T layout
    u16* vbh  = (u16*)(ws + 88080384ull);         // [84.6..92.6M) V proj; later wout
    float* cs = (float*)(ws + 96468992ull);       // 0.5MB
    float* sn = cs + TT * 64;                     // 0.5MB (total 97,517,568)
    u16* wq   = wqkv;                             // 8MB  [2048,2048]
    u16* wkv  = wqkv + 4194304;                   // 4MB  [1024,2048] = [k_w; v_w]
    u16* kk   = wqkv;                             // [B,KVH,T,128] aliases wq (dead)
    u16* wout = vbh;                              // out-proj weights bf16
    u16* y    = xh;                               // attn output aliases xh (dead)

    dim3 blk(256);

    // fused: x/q_w/k_w/v_w casts + rope tables (NTK base scaling)
    double base = 10000.0 * pow((double)TT / 1024.0, 128.0 / 126.0);
    prep_all<<<dim3(23040), blk, 0, stream>>>(x, q_w, k_w, v_w, xh, wq, wkv,
                                              cs, sn, (float)base);

    // Q projection + fused RMSNorm/RoPE/gain -> q2 (head-major, pre-scaled)
    const float pre_q = 0.08838834764831845f * 1.4426950408889634f;
    gemm256<256, 3><<<dim3(256), dim3(512), 0, stream>>>(xh, wq, q2, nullptr,
                                                         cs, sn, q_gain, pre_q);
    // KV projection: K cols fused RMSNorm/RoPE -> kk; V cols -> vbh
    gemm256<128, 4><<<dim3(256), dim3(512), 0, stream>>>(xh, wkv, kk, vbh,
                                                         cs, sn, nullptr, 0.f);

    // V -> [B,KVH,T/64,128,64] with per-32 key permutation
    transpose_v<<<dim3(TT / 64, 2, BB * NKV), blk, 0, stream>>>(vbh, vtb);

    // out-proj weights (wout aliases vbh; vbh dead after transpose_v)
    cast_f2b<<<dim3(4096), blk, 0, stream>>>(out_w, wout, DD * DD);

    // attention -> y (xh region; xh dead after gemms). Grid 512 uniform.
    attn_mfma<<<dim3(512), blk, 0, stream>>>(q2, kk, vtb, y);

    // output projection (fp32 out)
    gemm256<256, 2><<<dim3(256), dim3(512), 0, stream>>>(y, wout, out, nullptr,
                                                         nullptr, nullptr, nullptr, 0.f);
}

// Round 25
// 319.433 us; speedup vs baseline: 1.0210x; 1.0210x over previous
//
#include <hip/hip_runtime.h>
#include <hip/hip_bf16.h>
#include <math.h>

#define HEAD_DIM 128
#define NH 16
#define NKV 4
#define BB 4
#define TT 2048
#define DD 2048
#define ROWS (BB*TT)   // 8192

typedef unsigned short u16;
typedef unsigned int u32;
typedef __attribute__((ext_vector_type(8))) short short8;
typedef __attribute__((ext_vector_type(4))) float f32x4;
typedef __attribute__((ext_vector_type(16))) float f32x16;
typedef __attribute__((ext_vector_type(4))) unsigned short u16x4;

__device__ __forceinline__ float bf2f(u16 u) {
    union { unsigned int i; float f; } v; v.i = ((unsigned int)u) << 16; return v.f;
}
__device__ __forceinline__ u16 f2bf(float f) {
    union { float f; unsigned int i; } v; v.f = f;
    unsigned int r = v.i + 0x7FFFu + ((v.i >> 16) & 1u);   // round-to-nearest-even
    return (u16)(r >> 16);
}
__device__ __forceinline__ f32x4 mfma16(short8 a, short8 b, f32x4 c) {
    return __builtin_amdgcn_mfma_f32_16x16x32_bf16(a, b, c, 0, 0, 0);
}
__device__ __forceinline__ f32x16 mfma32(short8 a, short8 b, f32x16 c) {
    return __builtin_amdgcn_mfma_f32_32x32x16_bf16(a, b, c, 0, 0, 0);
}
__device__ __forceinline__ f32x16 zero16() {
    f32x16 z;
    #pragma unroll
    for (int i = 0; i < 16; ++i) z[i] = 0.f;
    return z;
}
// async global->LDS, 16B per lane; lds dest wave-uniform (HW adds lane*16)
__device__ __forceinline__ void gload_lds16(const u16* g, u16* l) {
    __builtin_amdgcn_global_load_lds(
        (const __attribute__((address_space(1))) unsigned int*)(const void*)g,
        (__attribute__((address_space(3))) unsigned int*)(void*)l, 16, 0, 0);
}

// ---------------------------------------------------------------------------
// fp32 -> bf16 cast (single-range)
// ---------------------------------------------------------------------------
__global__ __launch_bounds__(256)
void cast_f2b(const float* __restrict__ in, u16* __restrict__ out, int n)
{
    int i = (blockIdx.x * 256 + threadIdx.x) * 4;
    if (i >= n) return;
    float4 v = *(const float4*)(in + i);
    u16x4 o;
    o.x = f2bf(v.x); o.y = f2bf(v.y); o.z = f2bf(v.z); o.w = f2bf(v.w);
    *(u16x4*)(out + i) = o;
}

// ---------------------------------------------------------------------------
// prep_all: fused {x, q_w, k_w, v_w} casts + rope table build
// ---------------------------------------------------------------------------
__global__ __launch_bounds__(256)
void prep_all(const float* __restrict__ x,  const float* __restrict__ qw,
              const float* __restrict__ kw, const float* __restrict__ vw,
              u16* __restrict__ xh, u16* __restrict__ wq, u16* __restrict__ wkv,
              float* __restrict__ cs, float* __restrict__ sn, float base)
{
    const int bid = blockIdx.x, tid = threadIdx.x;
    if (bid < 22528) {
        const float* src; u16* dst; int i4;
        if (bid < 16384)      { src = x;  dst = xh;            i4 = bid; }
        else if (bid < 20480) { src = qw; dst = wq;            i4 = bid - 16384; }
        else if (bid < 21504) { src = kw; dst = wkv;           i4 = bid - 20480; }
        else                  { src = vw; dst = wkv + 1048576; i4 = bid - 21504; }
        int i = (i4 * 256 + tid) * 4;
        float4 v = *(const float4*)(src + i);
        u16x4 o;
        o.x = f2bf(v.x); o.y = f2bf(v.y); o.z = f2bf(v.z); o.w = f2bf(v.w);
        *(u16x4*)(dst + i) = o;
    } else {
        int idx = (bid - 22528) * 256 + tid;     // < TT*64
        int t = idx >> 6;
        int d = idx & 63;
        float inv = powf(base, -(float)(2 * d) / 128.0f);
        float f = (float)t * inv;
        cs[idx] = cosf(f);
        sn[idx] = sinf(f);
    }
}

// ---------------------------------------------------------------------------
// V transpose+relayout: vbh [B,T,KVH,128] -> vt [B,KVH, T/64, 128, 64] (bf16)
// kt-tiled; per-32 key permutation (bits 2<->3), proven rounds 5-24.
// ---------------------------------------------------------------------------
__global__ __launch_bounds__(256)
void transpose_v(const u16* __restrict__ vbh, u16* __restrict__ vtb)
{
    __shared__ u16 tile[64][72];
    const int tb = blockIdx.x;
    const int db = blockIdx.y;
    const int z  = blockIdx.z;        // b*NKV + kvh
    const int tid = threadIdx.x;

    {
        const int r = tid >> 2, cq = tid & 3;
        const u16* src = vbh + ((size_t)(((z >> 2) * TT + tb * 64 + r) * NKV + (z & 3))) * 128
                             + db * 64 + cq * 16;
        short8 s0 = *(const short8*)(src);
        short8 s1 = *(const short8*)(src + 8);
        #pragma unroll
        for (int e = 0; e < 8; ++e) tile[r][cq * 16 + e]     = (u16)s0[e];
        #pragma unroll
        for (int e = 0; e < 8; ++e) tile[r][cq * 16 + 8 + e] = (u16)s1[e];
    }
    __syncthreads();
    {
        const int d = tid >> 2, tq = tid & 3;
        __attribute__((aligned(16))) u16 tmp[16];
        #pragma unroll
        for (int e = 0; e < 16; ++e) {
            int esw = (e & 3) | ((e & 4) << 1) | ((e & 8) >> 1);  // swap bits 2,3
            tmp[e] = tile[tq * 16 + esw][d];
        }
        u16* dst = vtb + (((size_t)(z * (TT / 64) + tb) * 128 + (db * 64 + d)) << 6) + tq * 16;
        *(short8*)(dst)     = ((short8*)tmp)[0];
        *(short8*)(dst + 8) = ((short8*)tmp)[1];
    }
}

// ---------------------------------------------------------------------------
// 256-tile GEMM, counted-vmcnt pipeline (round-10 proven schedule), pair-row
// conflict-free LDS (round-16 proven). Best-measured config (R18/20/22:
// 319.9/320.9/325.1 us total).
// OUTMODE: 2 = fp32 C0 (N=2048)
//          3 = Q fused epilogue: RMSNorm+RoPE+gain -> C0 = q2 [B,NH,T,128]
//          4 = KV: K cols (bni<4) fused RMSNorm+RoPE -> C0 = kk [B,KVH,T,128];
//              V cols (bni>=4) plain bf16 -> C1 = vbh [B,T,KVH,128]
// Fused epilogue (VECTORIZED, round-18 proven):
//  (A) per-row sumsq via shfl + Sred cross-wave combine
//  (B) normalize -> full tile row-major bf16 in LDS (chunk-XOR swizzle)
//  (C) per-thread 8-elem rotate-half pair-chunks: 2 ds_read_b128 +
//      4 float4 table loads + rope + 2 coalesced 16B stores.
// Staging-LDS reuse is safe: vmcnt(0) executed at t=NT-2.
// ---------------------------------------------------------------------------
template<int BN, int OUTMODE>
__global__ __launch_bounds__(512, 2)
void gemm256(const u16* __restrict__ A, const u16* __restrict__ W,
             void* __restrict__ C0, void* __restrict__ C1,
             const float* __restrict__ CS, const float* __restrict__ SN,
             const float* __restrict__ GAIN, float PRE)
{
    constexpr int WN    = (BN == 256) ? 4 : 2;
    constexpr int MR    = (BN == 256) ? 8 : 4;
    constexpr int WROW  = (BN == 256) ? 128 : 64;
    constexpr int NT    = DD / 64;
    constexpr int NBI   = (BN == 256) ? 4 : 2;   // B stage issues per wave
    constexpr int BPR   = BN / 16;               // B pair-rows per wave

    __shared__ u16 LDSall[2 * 128 * 128 + 2 * (BN / 2) * 128];
    __shared__ float Sred[1024];
    u16* AsL = LDSall;
    u16* BsL = LDSall + 2 * 128 * 128;

    const int tid = threadIdx.x;
    const int w = tid >> 6, l = tid & 63;
    const int lq = l & 15, lg = l >> 4;
    const int wmi = (WN == 4) ? (w >> 2) : (w >> 1);
    const int wni = w & (WN - 1);

    int bmi, bni;
    {
        const int bid = blockIdx.x;
        const int wg = (bid & 7) * 32 + (bid >> 3);
        const int st = wg >> 2, wi = wg & 3;
        const int sty = st >> 2, stx = st & 3;
        bmi = sty * 2 + (wi >> 1);
        bni = stx * 2 + (wi & 1);
    }
    const int bm = bmi * 256, bn = bni * BN;

    const int sro = l >> 4;          // staging row-in-issue 0..3
    const int sch = l & 15;          // staging 16B chunk 0..15

    f32x4 acc[MR][4];
    #pragma unroll
    for (int m = 0; m < MR; ++m)
        #pragma unroll
        for (int n = 0; n < 4; ++n) acc[m][n] = (f32x4){0.f, 0.f, 0.f, 0.f};

    auto stage = [&](int buf, int t) {
        const size_t ko = (size_t)t * 64;
        u16* Ad = AsL + buf * (128 * 128);
        u16* Bd = BsL + buf * ((BN / 2) * 128);
        #pragma unroll
        for (int j = 0; j < 4; ++j) {
            int rp = w * 16 + j * 4 + sro;
            int cg = sch ^ (rp & 15);
            gload_lds16(A + (size_t)(bm + 2 * rp + (cg >> 3)) * DD + ko + (cg & 7) * 8,
                        Ad + (w * 16 + j * 4) * 128);
        }
        #pragma unroll
        for (int j = 0; j < NBI; ++j) {
            int rp = w * BPR + j * 4 + sro;
            int cg = sch ^ (rp & 15);
            gload_lds16(W + (size_t)(bn + 2 * rp + (cg >> 3)) * DD + ko + (cg & 7) * 8,
                        Bd + (w * BPR + j * 4) * 128);
        }
    };

    stage(0, 0);
    stage(1, 1);
    if constexpr (BN == 256) asm volatile("s_waitcnt vmcnt(8)" ::: "memory");
    else                     asm volatile("s_waitcnt vmcnt(6)" ::: "memory");
    __builtin_amdgcn_s_barrier();
    __builtin_amdgcn_sched_barrier(0);

    const int mh = lq >> 1;              // pair-row sub-offset
    const int e8 = (lq & 1) << 3;        // parity -> chunk bit 3
    for (int t = 0; t < NT; ++t) {
        const int buf = t & 1;
        const u16* Ab = AsL + buf * (128 * 128);
        const u16* Bb = BsL + buf * ((BN / 2) * 128);
        #pragma unroll
        for (int ks = 0; ks < 2; ++ks) {
            short8 af[MR], bf[4];
            #pragma unroll
            for (int m = 0; m < MR; ++m) {
                int rp = wmi * (WROW / 2) + m * 8 + mh;
                af[m] = *(const short8*)(Ab + rp * 128 + (((e8 + ks * 4 + lg) ^ (rp & 15)) << 3));
            }
            #pragma unroll
            for (int n = 0; n < 4; ++n) {
                int rp = wni * 32 + n * 8 + mh;
                bf[n] = *(const short8*)(Bb + rp * 128 + (((e8 + ks * 4 + lg) ^ (rp & 15)) << 3));
            }
            __builtin_amdgcn_s_setprio(1);
            #pragma unroll
            for (int m = 0; m < MR; ++m)
                #pragma unroll
                for (int n = 0; n < 4; ++n)
                    acc[m][n] = mfma16(af[m], bf[n], acc[m][n]);
            __builtin_amdgcn_s_setprio(0);
        }

        if (t + 1 < NT) {
            __builtin_amdgcn_sched_barrier(0);
            __builtin_amdgcn_s_barrier();
            if (t + 2 < NT) {
                stage(buf, t + 2);
                if constexpr (BN == 256) asm volatile("s_waitcnt vmcnt(8)" ::: "memory");
                else                     asm volatile("s_waitcnt vmcnt(6)" ::: "memory");
            } else {
                asm volatile("s_waitcnt vmcnt(0)" ::: "memory");
            }
            __builtin_amdgcn_s_barrier();
            __builtin_amdgcn_sched_barrier(0);
        }
    }

    if constexpr (OUTMODE == 2) {
        #pragma unroll
        for (int m = 0; m < MR; ++m) {
            int grow = bm + wmi * WROW + m * 16 + lg * 4;
            #pragma unroll
            for (int n = 0; n < 4; ++n) {
                int col = wni * 64 + n * 16 + lq;
                #pragma unroll
                for (int q = 0; q < 4; ++q)
                    ((float*)C0)[(size_t)(grow + q) * 2048 + bn + col] = acc[m][n][q];
            }
        }
    } else {
        const bool isK = (OUTMODE == 3) ? true : (bni < 4);
        u16* E = LDSall;
        constexpr int RS = (OUTMODE == 3) ? 256 : 128;   // E row stride (u16)
        constexpr int CM = (OUTMODE == 3) ? 31 : 15;     // chunk XOR mask

        if (isK) {
            __syncthreads();            // all waves done with K-loop LDS reads
            // (A) per-row sumsq partials
            #pragma unroll
            for (int m = 0; m < MR; ++m) {
                f32x4 ps = acc[m][0] * acc[m][0];
                #pragma unroll
                for (int n = 1; n < 4; ++n) ps += acc[m][n] * acc[m][n];
                #pragma unroll
                for (int q = 0; q < 4; ++q) {
                    float v = ps[q];
                    v += __shfl_xor(v, 1, 64);
                    v += __shfl_xor(v, 2, 64);
                    v += __shfl_xor(v, 4, 64);
                    v += __shfl_xor(v, 8, 64);
                    if (lq == 0) {
                        int lr = m * 16 + lg * 4 + q;
                        if constexpr (OUTMODE == 3)
                            Sred[wmi * 512 + lr * 4 + (wni >> 1) * 2 + (wni & 1)] = v;
                        else
                            Sred[wmi * 128 + lr * 2 + (wni & 1)] = v;
                    }
                }
            }
            __syncthreads();
            // (B) normalize -> E row-major bf16 (chunk-XOR swizzled)
            #pragma unroll
            for (int m = 0; m < MR; ++m) {
                f32x4 rs4;
                #pragma unroll
                for (int q = 0; q < 4; ++q) {
                    int lr = m * 16 + lg * 4 + q;
                    float tot;
                    if constexpr (OUTMODE == 3)
                        tot = Sred[wmi * 512 + lr * 4 + (wni >> 1) * 2]
                            + Sred[wmi * 512 + lr * 4 + (wni >> 1) * 2 + 1];
                    else
                        tot = Sred[wmi * 128 + lr * 2]
                            + Sred[wmi * 128 + lr * 2 + 1];
                    rs4[q] = 1.0f / sqrtf(tot * (1.0f / 128.0f) + 1.1920929e-7f);
                }
                #pragma unroll
                for (int n = 0; n < 4; ++n) {
                    #pragma unroll
                    for (int q = 0; q < 4; ++q) {
                        int rloc = wmi * WROW + m * 16 + lg * 4 + q;
                        int col  = wni * 64 + n * 16 + lq;
                        int eoff = rloc * RS + ((((col >> 3) ^ (rloc & CM)) << 3) | (col & 7));
                        E[eoff] = f2bf(acc[m][n][q] * rs4[q]);
                    }
                }
            }
            __syncthreads();
            // (C) rotate-half rope + coalesced vector store
            constexpr int NU = (OUTMODE == 3) ? 8 : 4;
            #pragma unroll
            for (int u = 0; u < NU; ++u) {
                int gu = u * 512 + tid;
                int pair = gu & 7;
                int rloc = (gu >> 3) & 255;
                int hsub = (OUTMODE == 3) ? (gu >> 11) : 0;
                int d0 = pair * 8;
                int cl = hsub * 128 + d0;
                int ch = cl + 64;
                short8 lo = *(const short8*)&E[rloc * RS + (((cl >> 3) ^ (rloc & CM)) << 3)];
                short8 hi2 = *(const short8*)&E[rloc * RS + (((ch >> 3) ^ (rloc & CM)) << 3)];
                int grow = bm + rloc;
                int t = grow & 2047, bb = grow >> 11;
                float4 c0 = *(const float4*)&CS[t * 64 + d0];
                float4 c1 = *(const float4*)&CS[t * 64 + d0 + 4];
                float4 s0 = *(const float4*)&SN[t * 64 + d0];
                float4 s1 = *(const float4*)&SN[t * 64 + d0 + 4];
                float cc[8] = {c0.x, c0.y, c0.z, c0.w, c1.x, c1.y, c1.z, c1.w};
                float ssv[8] = {s0.x, s0.y, s0.z, s0.w, s1.x, s1.y, s1.z, s1.w};
                float g = 1.f;
                size_t obase;
                if constexpr (OUTMODE == 3) {
                    int h = (bn >> 7) + hsub;
                    g = GAIN[h] * PRE;
                    obase = ((size_t)(bb * NH + h) * TT + t) << 7;
                } else {
                    obase = ((size_t)(bb * NKV + bni) * TT + t) << 7;
                }
                union { u16 e[8]; short8 s8; } o1, o2;
                #pragma unroll
                for (int e = 0; e < 8; ++e) {
                    float x1 = bf2f((u16)lo[e]);
                    float x2 = bf2f((u16)hi2[e]);
                    o1.e[e] = f2bf((x1 * cc[e] + x2 * ssv[e]) * g);
                    o2.e[e] = f2bf((-x1 * ssv[e] + x2 * cc[e]) * g);
                }
                *(short8*)((u16*)C0 + obase + d0)      = o1.s8;
                *(short8*)((u16*)C0 + obase + 64 + d0) = o2.s8;
            }
        } else {
            // V columns (OUTMODE 4, bni>=4): plain bf16 -> vbh [B,T,KVH,128]
            #pragma unroll
            for (int m = 0; m < MR; ++m) {
                int growb = bm + wmi * WROW + m * 16 + lg * 4;
                #pragma unroll
                for (int n = 0; n < 4; ++n) {
                    int cg = bn + wni * 64 + n * 16 + lq - 512;
                    #pragma unroll
                    for (int q = 0; q < 4; ++q)
                        ((u16*)C1)[(size_t)(growb + q) * 512 + cg] = f2bf(acc[m][n][q]);
                }
            }
        }
    }
}

// ---------------------------------------------------------------------------
// Causal attention — round-16 version (counted-vmcnt staging, conflict-free
// 16-chunk XOR LDS, fold-balanced, XCD-mapped). Proven passed.
// ---------------------------------------------------------------------------
__global__ __launch_bounds__(256, 2)
void attn_mfma(const u16* __restrict__ qg,   // [B,NH,T,128] head-major, pre-scaled
               const u16* __restrict__ kg,   // [B,KVH,T,128]
               const u16* __restrict__ vtg,  // [B,KVH,T/64,128,64] key-permuted
               u16* __restrict__ yg)         // [B,T,NH,128]
{
    __shared__ u16 Ks[2][64 * 128];   // [key][256B]      16-chunk XOR
    __shared__ u16 Vs[2][64 * 128];   // [d-pair][256B]   16-chunk XOR

    const int tid = threadIdx.x, wid = tid >> 6, l = tid & 63;
    const int lq = l & 31, hi = l >> 5, hi4 = hi << 2;

    const int bid = blockIdx.x;
    const int xcd  = bid & 7;
    const int s    = bid >> 3;
    const int gsub = s >> 5;
    const int hh   = (s >> 3) & 3;
    const int fold = s & 7;
    const int g    = xcd + (gsub << 3);
    const int b = g >> 2, kvh = g & 3;
    const int h = kvh * 4 + hh;

    const u16* kg_bh = kg + (((size_t)g * TT) << 7);
    const u16* vt_bh = vtg + (size_t)g * (TT / 64) * 8192;
    const u16* q_bh  = qg + (((size_t)(b * NH + h) * TT) << 7);

    const int nta = 2 * fold + 2;
    const int NT  = 34;

    const int sro = l >> 4;              // row-in-issue 0..3
    const int sch = l & 15;              // 16B chunk 0..15

    auto stage = [&](int buf, int kt) {
        #pragma unroll
        for (int i = 0; i < 4; ++i) {
            int kr = wid * 16 + i * 4 + sro;
            int cgk = sch ^ (kr & 15);
            gload_lds16(kg_bh + (((size_t)(kt * 64 + kr)) << 7) + (cgk << 3),
                        &Ks[buf][(wid * 16 + i * 4) << 7]);
            int rp = wid * 16 + i * 4 + sro;
            int cgv = sch ^ (rp & 15);
            gload_lds16(vt_bh + (size_t)kt * 8192 + ((2 * rp + (cgv >> 3)) << 6) + ((cgv & 7) << 3),
                        &Vs[buf][(wid * 16 + i * 4) << 7]);
        }
    };

    stage(0, 0);
    stage(1, 1);
    asm volatile("s_waitcnt vmcnt(8)" ::: "memory");
    __builtin_amdgcn_s_barrier();
    __builtin_amdgcn_sched_barrier(0);

    int step = 0;

    for (int seg = 0; seg < 2; ++seg) {
        const int qblk = seg ? (15 - fold) : fold;
        const int nseg = seg ? (32 - 2 * fold) : nta;
        const int qrow = qblk * 128 + wid * 32 + lq;
        const int diag = (qblk * 128 + wid * 32) >> 6;

        const u16* qptr = q_bh + ((size_t)qrow << 7) + hi * 8;
        short8 qf[8];
        #pragma unroll
        for (int q = 0; q < 8; ++q)
            qf[q] = *(const short8*)(qptr + q * 16);

        f32x16 accO[4];
        #pragma unroll
        for (int d = 0; d < 4; ++d) accO[d] = zero16();
        float m2 = -1e30f, lr = 0.f;

        for (int kt = 0; kt < nseg; ++kt, ++step) {
            const int buf = step & 1;

            if (kt <= diag) {
                // ---- S^T = K·Q (16 MFMA) ----
                const u16* Kc = Ks[buf];
                f32x16 accS0 = zero16(), accS1 = zero16();
                __builtin_amdgcn_s_setprio(1);
                #pragma unroll
                for (int ss = 0; ss < 8; ++ss) {
                    int c = ((2 * ss + hi) ^ (lq & 15)) << 3;
                    short8 kf0 = *(const short8*)(Kc + (lq << 7) + c);
                    accS0 = mfma32(kf0, qf[ss], accS0);
                    short8 kf1 = *(const short8*)(Kc + ((32 + lq) << 7) + c);
                    accS1 = mfma32(kf1, qf[ss], accS1);
                }
                __builtin_amdgcn_s_setprio(0);

                // ---- scores + causal mask (diag tile only) ----
                float p[32];
                if (kt == diag) {
                    #pragma unroll
                    for (int r = 0; r < 16; ++r) {
                        int key0 = kt * 64 + (r & 3) + 8 * (r >> 2) + hi4;
                        p[r]      = (key0      > qrow) ? -INFINITY : accS0[r];
                        p[16 + r] = (key0 + 32 > qrow) ? -INFINITY : accS1[r];
                    }
                } else {
                    #pragma unroll
                    for (int r = 0; r < 16; ++r) { p[r] = accS0[r]; p[16 + r] = accS1[r]; }
                }

                // ---- row max ----
                float t16[16];
                #pragma unroll
                for (int i = 0; i < 16; ++i) t16[i] = fmaxf(p[i], p[i + 16]);
                #pragma unroll
                for (int i = 0; i < 8; ++i) t16[i] = fmaxf(t16[i], t16[i + 8]);
                #pragma unroll
                for (int i = 0; i < 4; ++i) t16[i] = fmaxf(t16[i], t16[i + 4]);
                float pm = fmaxf(fmaxf(t16[0], t16[1]), fmaxf(t16[2], t16[3]));
                pm = fmaxf(pm, __shfl_xor(pm, 32, 64));

                // ---- defer-max ----
                float mn = m2;
                if (!__all(pm - m2 <= 8.0f)) {
                    mn = fmaxf(m2, pm);
                    float al = exp2f(m2 - mn);
                    lr *= al;
                    #pragma unroll
                    for (int d = 0; d < 4; ++d) accO[d] *= al;
                    m2 = mn;
                }

                // ---- exp2 + row sum ----
                #pragma unroll
                for (int r = 0; r < 32; ++r) p[r] = exp2f(p[r] - mn);
                #pragma unroll
                for (int i = 0; i < 16; ++i) t16[i] = p[i] + p[i + 16];
                #pragma unroll
                for (int i = 0; i < 8; ++i) t16[i] += t16[i + 8];
                #pragma unroll
                for (int i = 0; i < 4; ++i) t16[i] += t16[i + 4];
                float rs = (t16[0] + t16[1]) + (t16[2] + t16[3]);
                rs += __shfl_xor(rs, 32, 64);
                lr += rs;

                // ---- P -> bf16 B-fragments via packed cvt (RTNE) ----
                short8 pfrag[4];
                #pragma unroll
                for (int kb = 0; kb < 2; ++kb)
                    #pragma unroll
                    for (int c = 0; c < 2; ++c) {
                        union { u32 u[4]; short8 s8; } f;
                        #pragma unroll
                        for (int j = 0; j < 4; ++j) {
                            __hip_bfloat162 hb = __float22bfloat162_rn(
                                make_float2(p[kb * 16 + 8 * c + 2 * j],
                                            p[kb * 16 + 8 * c + 2 * j + 1]));
                            f.u[j] = *reinterpret_cast<u32*>(&hb);
                        }
                        pfrag[kb * 2 + c] = f.s8;
                    }

                // ---- O^T += V^T · P^T (16 MFMA), pair-row V reads ----
                const u16* Vc = Vs[buf];
                const int rv = lq >> 1;
                const int ev = (lq & 1) << 3;
                #pragma unroll
                for (int d = 0; d < 4; ++d) {
                    const u16* vr8 = Vc + ((d * 16 + rv) << 7);
                    short8 vf0 = *(const short8*)(vr8 + (((ev + 0 + hi) ^ rv) << 3));
                    short8 vf1 = *(const short8*)(vr8 + (((ev + 2 + hi) ^ rv) << 3));
                    short8 vf2 = *(const short8*)(vr8 + (((ev + 4 + hi) ^ rv) << 3));
                    short8 vf3 = *(const short8*)(vr8 + (((ev + 6 + hi) ^ rv) << 3));
                    __builtin_amdgcn_s_setprio(1);
                    accO[d] = mfma32(vf0, pfrag[0], accO[d]);
                    accO[d] = mfma32(vf1, pfrag[1], accO[d]);
                    accO[d] = mfma32(vf2, pfrag[2], accO[d]);
                    accO[d] = mfma32(vf3, pfrag[3], accO[d]);
                    __builtin_amdgcn_s_setprio(0);
                }
            }

            // ---- pipeline advance (all waves, uniform) ----
            if (step + 1 < NT) {
                __builtin_amdgcn_sched_barrier(0);
                __builtin_amdgcn_s_barrier();
                if (step + 2 < NT) {
                    int tn = step + 2;
                    stage(buf, (tn < nta) ? tn : tn - nta);
                    asm volatile("s_waitcnt vmcnt(8)" ::: "memory");
                } else {
                    asm volatile("s_waitcnt vmcnt(0)" ::: "memory");
                }
                __builtin_amdgcn_s_barrier();
                __builtin_amdgcn_sched_barrier(0);
            }
        }

        // ---- segment epilogue: normalize (lr lane-uniform) and store ----
        float inv = 1.0f / lr;
        u16* yrow = yg + ((size_t)((b * TT + qrow) * NH + h) << 7);
        #pragma unroll
        for (int d = 0; d < 4; ++d)
            #pragma unroll
            for (int r = 0; r < 4; ++r) {
                u16x4 o;
                #pragma unroll
                for (int q = 0; q < 4; ++q) o[q] = f2bf(accO[d][4 * r + q] * inv);
                *(u16x4*)(yrow + d * 32 + 8 * r + hi4) = o;
            }
    }
}

// ---------------------------------------------------------------------------
extern "C" void kernel_launch(void* const* d_in, const int* in_sizes, int n_in,
                              void* d_out, int out_size, void* d_ws, size_t ws_size,
                              hipStream_t stream)
{
    const float* x      = (const float*)d_in[0];
    const float* q_w    = (const float*)d_in[1];
    const float* k_w    = (const float*)d_in[2];
    const float* v_w    = (const float*)d_in[3];
    const float* out_w  = (const float*)d_in[4];
    const float* q_gain = (const float*)d_in[5];
    float* out = (float*)d_out;

    char* ws = (char*)d_ws;
    u16* q2   = (u16*)(ws);                       // [0,32M)   fused Q out [B,NH,T,128]
    u16* xh   = (u16*)(ws + 33554432ull);         // [32,64M)  x bf16; later y
    u16* wqkv = (u16*)(ws + 67108864ull);         // [64,76.6M) wq+wkv; wq later kk
    u16* vtb  = (u16*)(ws + 79691776ull);         // [76.6..84.6M) V^T layout
    u16* vbh  = (u16*)(ws + 88080384ull);         // [84.6..92.6M) V proj; later wout
    float* cs = (float*)(ws + 96468992ull);       // 0.5MB
    float* sn = cs + TT * 64;                     // 0.5MB (total 97,517,568)
    u16* wq   = wqkv;                             // 8MB  [2048,2048]
    u16* wkv  = wqkv + 4194304;                   // 4MB  [1024,2048] = [k_w; v_w]
    u16* kk   = wqkv;                             // [B,KVH,T,128] aliases wq (dead)
    u16* wout = vbh;                              // out-proj weights bf16
    u16* y    = xh;                               // attn output aliases xh (dead)

    dim3 blk(256);

    // fused: x/q_w/k_w/v_w casts + rope tables (NTK base scaling)
    double base = 10000.0 * pow((double)TT / 1024.0, 128.0 / 126.0);
    prep_all<<<dim3(23040), blk, 0, stream>>>(x, q_w, k_w, v_w, xh, wq, wkv,
                                              cs, sn, (float)base);

    // Q projection + fused RMSNorm/RoPE/gain -> q2 (head-major, pre-scaled)
    const float pre_q = 0.08838834764831845f * 1.4426950408889634f;
    gemm256<256, 3><<<dim3(256), dim3(512), 0, stream>>>(xh, wq, q2, nullptr,
                                                         cs, sn, q_gain, pre_q);
    // KV projection: K cols fused RMSNorm/RoPE -> kk; V cols -> vbh
    gemm256<128, 4><<<dim3(256), dim3(512), 0, stream>>>(xh, wkv, kk, vbh,
                                                         cs, sn, nullptr, 0.f);

    // V -> [B,KVH,T/64,128,64] with per-32 key permutation
    transpose_v<<<dim3(TT / 64, 2, BB * NKV), blk, 0, stream>>>(vbh, vtb);

    // out-proj weights (wout aliases vbh; vbh dead after transpose_v)
    cast_f2b<<<dim3(4096), blk, 0, stream>>>(out_w, wout, DD * DD);

    // attention -> y (xh region; xh dead after gemms). Grid 512 uniform.
    attn_mfma<<<dim3(512), blk, 0, stream>>>(q2, kk, vtb, y);

    // output projection (fp32 out)
    gemm256<256, 2><<<dim3(256), dim3(512), 0, stream>>>(y, wout, out, nullptr,
                                                         nullptr, nullptr, nullptr, 0.f);
}